// Round 10
// baseline (483.713 us; speedup 1.0000x reference)
//
#include <hip/hip_runtime.h>
#include <hip/hip_bf16.h>

// Problem dims (fixed): T=1024, B=32, DIN=256, H=256, AA=21, L=2
#define T_DIM 1024
#define B_DIM 32
#define DIN_DIM 256
#define H_DIM 256
#define AA_DIM 21
#define M_ROWS (B_DIM * T_DIM)   // 32768 rows, row index = b*T + t everywhere

typedef __attribute__((ext_vector_type(8))) short bf16x8;   // 8 bf16 = 4 VGPRs
typedef __attribute__((ext_vector_type(4))) float f32x4;

typedef __attribute__((address_space(3))) void lds_void;
typedef const __attribute__((address_space(1))) void glb_void;

#define LOG2E_F 1.44269504088896340736f

__device__ __forceinline__ void gload_lds16(const void* g, void* l) {
    // global gather (per-lane addr) -> LDS at (wave-uniform base + lane*16)
    __builtin_amdgcn_global_load_lds((glb_void*)g, (lds_void*)l, 16, 0, 0);
}

__device__ __forceinline__ float b2f(unsigned short v) {
    unsigned u = ((unsigned)v) << 16;
    float f;
    __builtin_memcpy(&f, &u, 4);
    return f;
}

__device__ __forceinline__ unsigned short f2bu(float f) {
    __hip_bfloat16 h = __float2bfloat16(f);
    unsigned short u;
    __builtin_memcpy(&u, &h, 2);
    return u;
}

// ---------------------------------------------------------------------------
// All weight/input converts fused into ONE dispatch (vectorized bulk paths).
// seg0: x -> xb bf16 (float4/thread)   seg1: w_l0 -> w0t (2048,256) interleaved
// seg2: w_l1 -> w1t (2048,512)         seg3: fc1_w -> fc1wb
// seg4: lp_w -> lpwb (32,256) padded   seg5: exp2-ready scale/bias per U col
#define CVT_V0 2097152            // 8388608 / 4
#define CVT_N1 524288
#define CVT_N2 1048576
#define CVT_V3 32768              // 131072 / 4
#define CVT_N4 8192
#define CVT_N5 4096
#define CVT_TOT (CVT_V0 + CVT_N1 + CVT_N2 + CVT_V3 + CVT_N4 + CVT_N5)
__global__ __launch_bounds__(256) void cvt_all(
    const float* __restrict__ x,  const float* __restrict__ w0,
    const float* __restrict__ w1, const float* __restrict__ fcw,
    const float* __restrict__ lpw,
    const float* __restrict__ b0, const float* __restrict__ b1,
    __hip_bfloat16* __restrict__ xb,  __hip_bfloat16* __restrict__ w0t,
    __hip_bfloat16* __restrict__ w1t, __hip_bfloat16* __restrict__ fcwb,
    __hip_bfloat16* __restrict__ lpwb,
    float* __restrict__ sc0, float* __restrict__ bs0,
    float* __restrict__ sc1, float* __restrict__ bs1)
{
    int i = blockIdx.x * 256 + threadIdx.x;
    if (i < CVT_V0) {
        float4 v = ((const float4*)x)[i];
        ushort4 o = { f2bu(v.x), f2bu(v.y), f2bu(v.z), f2bu(v.w) };
        ((ushort4*)xb)[i] = o;
        return;
    }
    i -= CVT_V0;
    if (i < CVT_N1) {   // w0t, K=256; input flat ((kk*2+dir)*4+k)*H + h
        int kk = i >> 11, rem = i & 2047;
        int dir = rem >> 10, k = (rem >> 8) & 3, h = rem & 255;
        w0t[(long)(dir * 1024 + h * 4 + k) * 256 + kk] = __float2bfloat16(w0[i]);
        return;
    }
    i -= CVT_N1;
    if (i < CVT_N2) {   // w1t, K=512
        int kk = i >> 11, rem = i & 2047;
        int dir = rem >> 10, k = (rem >> 8) & 3, h = rem & 255;
        w1t[(long)(dir * 1024 + h * 4 + k) * 512 + kk] = __float2bfloat16(w1[i]);
        return;
    }
    i -= CVT_N2;
    if (i < CVT_V3) {
        float4 v = ((const float4*)fcw)[i];
        ushort4 o = { f2bu(v.x), f2bu(v.y), f2bu(v.z), f2bu(v.w) };
        ((ushort4*)fcwb)[i] = o;
        return;
    }
    i -= CVT_V3;
    if (i < CVT_N4) {   // lpwb (32,256), zero-padded past row 20
        int n = i >> 8, k = i & 255;
        lpwb[i] = __float2bfloat16(n < AA_DIM ? lpw[n * 256 + k] : 0.0f);
        return;
    }
    i -= CVT_N4;
    if (i < CVT_N5) {   // scale/bias vectors, 2048 per layer
        int layer = i >> 11, n = i & 2047;
        int k = n & 3, h = (n >> 2) & 255, dir = n >> 10;
        const float* bb = layer ? b1 : b0;
        float sc = 1.0f, bs = 0.0f;
        if (k == 1) { sc = -LOG2E_F; bs = -LOG2E_F * bb[(dir * 2 + 0) * 256 + h]; }
        if (k == 2) { sc = -LOG2E_F; bs = -LOG2E_F * bb[(dir * 2 + 1) * 256 + h]; }
        if (layer) { sc1[n] = sc; bs1[n] = bs; }
        else       { sc0[n] = sc; bs0[n] = bs; }
    }
}

// ---------------------------------------------------------------------------
// bf16 GEMM: C = fma(A*Bt^T, scale_n, bias_n), 128x128 tile, BK=64,
// XCD-aware 1-D grid swizzle, swizzled global_load_lds staging (0 conflicts),
// two-pass stride-132 LDS epilogue (0 conflicts, full-line stores).
// U2OUT=1: write scan-friendly layout [beta=b*8+dir*4+hg][t][64h x 4k]
//          (beta slice = contiguous 512 KB; per-thread store stays 32B).
// U2OUT=0: plain row-major C(M,N).
template<int U2OUT>
__global__ __launch_bounds__(256) void gemm_bf16(
    const __hip_bfloat16* __restrict__ A,
    const __hip_bfloat16* __restrict__ Bt,
    const float* __restrict__ bias,    // len N or nullptr
    const float* __restrict__ scale,   // len N or nullptr (1.0)
    __hip_bfloat16* __restrict__ C,
    int M, int N, int K, int nbShift)
{
    __shared__ __align__(16) char smb[32768];

    const int tid  = threadIdx.x;
    const int lane = tid & 63;
    const int wave = tid >> 6;
    const int wm = wave & 1;
    const int wn = wave >> 1;

    const int L   = blockIdx.x;
    const int s   = L >> 3;
    const int nb  = s & ((1 << nbShift) - 1);
    const int mb  = ((s >> nbShift) << 3) + (L & 7);
    const long n0 = (long)nb * 128;
    const long m0 = (long)mb * 128;

    f32x4 acc[4][4] = {};

    const int ldrow = lane >> 2;
    const int ldq   = lane & 3;
    const int gq    = ldq ^ ((ldrow >> 1) & 3);
    const int gkoff = gq * 8;

    const int fr = lane & 15;
    const int kq = lane >> 4;
    const int sw = (kq ^ ((fr >> 1) & 3)) * 16;

    for (int kb = 0; kb < K; kb += 64) {
        __syncthreads();
#pragma unroll
        for (int i = 0; i < 4; ++i) {
            const int cid = wave * 4 + i;
            const int rc  = cid >> 1;
            const int kh  = cid & 1;
            const long row = rc * 16 + ldrow;
            const int koff = kb + kh * 32 + gkoff;
            gload_lds16(A  + (m0 + row) * (long)K + koff,
                        smb + rc * 2048 + kh * 1024);
            gload_lds16(Bt + (n0 + row) * (long)K + koff,
                        smb + 16384 + rc * 2048 + kh * 1024);
        }
        __syncthreads();

#pragma unroll
        for (int ss = 0; ss < 2; ++ss) {
            bf16x8 af[4], bfv[4];
#pragma unroll
            for (int i = 0; i < 4; ++i) {
                af[i]  = *(const bf16x8*)(smb + (wm * 4 + i) * 2048 + ss * 1024 + fr * 64 + sw);
                bfv[i] = *(const bf16x8*)(smb + 16384 + (wn * 4 + i) * 2048 + ss * 1024 + fr * 64 + sw);
            }
#pragma unroll
            for (int i = 0; i < 4; ++i)
#pragma unroll
                for (int j = 0; j < 4; ++j)
                    acc[i][j] = __builtin_amdgcn_mfma_f32_16x16x32_bf16(
                        af[i], bfv[j], acc[i][j], 0, 0, 0);
        }
    }

    // ---- epilogue: C/D layout col=lane&15, row=(lane>>4)*4+reg ----
    const int col_l = lane & 15;
    const int row_l = (lane >> 4) * 4;
    __hip_bfloat16* smC = (__hip_bfloat16*)smb;   // stride 132 bf16
#pragma unroll
    for (int p = 0; p < 2; ++p) {
        __syncthreads();
        if (wm == p) {
#pragma unroll
            for (int j = 0; j < 4; ++j) {
                const long gc = n0 + wn * 64 + j * 16 + col_l;
                const float bv = bias ? bias[gc] : 0.0f;
                const float av = scale ? scale[gc] : 1.0f;
#pragma unroll
                for (int i = 0; i < 4; ++i)
#pragma unroll
                    for (int r = 0; r < 4; ++r)
                        smC[(i * 16 + row_l + r) * 132 + wn * 64 + j * 16 + col_l] =
                            __float2bfloat16(__builtin_fmaf(acc[i][j][r], av, bv));
            }
        }
        __syncthreads();
        const int cb = (tid & 7) * 16;      // col start (elems), 32B/thread
#pragma unroll
        for (int s2 = 0; s2 < 2; ++s2) {
            const int rr = s2 * 32 + (tid >> 3);
            const long gr = m0 + p * 64 + rr;
            bf16x8 v0 = *(const bf16x8*)(smC + rr * 132 + cb);
            bf16x8 v1 = *(const bf16x8*)(smC + rr * 132 + cb + 8);
            if (U2OUT) {
                const int bI  = (int)(gr >> 10);
                const int t   = (int)(gr & 1023);
                const long gc0 = n0 + cb;
                const int dir = (int)(gc0 >> 10);
                const int hg  = ((int)gc0 >> 8) & 3;
                const int beta = bI * 8 + dir * 4 + hg;
                const long base = ((long)beta * 1024 + t) * 256 + (gc0 & 255);
                *(bf16x8*)(C + base)     = v0;
                *(bf16x8*)(C + base + 8) = v1;
            } else {
                *(bf16x8*)(C + gr * (long)N + n0 + cb)     = v0;
                *(bf16x8*)(C + gr * (long)N + n0 + cb + 8) = v1;
            }
        }
    }
}

// ---------------------------------------------------------------------------
// SRU scan, producer-consumer. 256 blocks x 256 threads; block beta owns 64
// recurrences (b=beta>>3, dir=(beta>>2)&1, hg=beta&3; h=hg*64+lane). U2 slice
// for beta is contiguous 512 KB: [t][64h x 4k gates]. Waves 1-3 stream U2 into
// a double-buffered 64-step LDS ring (2x32 KB); wave 0 runs the recurrence
// from LDS (~30 cyc/step chain). One barrier per 64-step batch -> fill of
// batch i+1 (HBM latency) fully overlaps consume of batch i.
#define SCAN_S 64
#define SCAN_NB (T_DIM / SCAN_S)   // 16
__global__ __launch_bounds__(256) void sru_scan(
    const __hip_bfloat16* __restrict__ U2,
    const float* __restrict__ wc,    // (2,2,H)
    __hip_bfloat16* __restrict__ hout)
{
    __shared__ __align__(16) char lds[2 * SCAN_S * 512];   // 65536 B
    const int tid  = threadIdx.x;
    const int wave = tid >> 6;
    const int lane = tid & 63;
    const int beta = blockIdx.x;
    const int b    = beta >> 3;
    const int dir  = (beta >> 2) & 1;
    const int hg   = beta & 3;
    const int h    = hg * 64 + lane;

    const char* gslice = (const char*)U2 + (size_t)beta * (1024 * 512);

    // consumer state (wave 0 only uses it)
    const float nvf = -LOG2E_F * wc[(dir * 2 + 0) * H_DIM + h];
    const float nvr = -LOG2E_F * wc[(dir * 2 + 1) * H_DIM + h];
    __hip_bfloat16* hp = hout + ((long)(b * 1024 + (dir ? 1023 : 0))) * 512 + dir * 256 + h;
    const long hstep = dir ? -512L : 512L;
    float c = 0.0f;

    // prologue: producers fill half 0 with batch 0
    if (wave > 0) {
        for (int s2 = wave - 1; s2 < SCAN_S; s2 += 3) {
            const int t = dir ? (1023 - s2) : s2;
            uint2 v = *(const uint2*)(gslice + (size_t)t * 512 + (lane << 3));
            *(uint2*)(lds + s2 * 512 + (lane << 3)) = v;
        }
    }
    __syncthreads();

    for (int bat = 0; bat < SCAN_NB; ++bat) {
        if (wave > 0) {
            if (bat + 1 < SCAN_NB) {
                char* half = lds + ((bat + 1) & 1) * (SCAN_S * 512);
                const int tb = (bat + 1) * SCAN_S;
                for (int s2 = wave - 1; s2 < SCAN_S; s2 += 3) {
                    const int tl = tb + s2;
                    const int t  = dir ? (1023 - tl) : tl;
                    uint2 v = *(const uint2*)(gslice + (size_t)t * 512 + (lane << 3));
                    *(uint2*)(half + s2 * 512 + (lane << 3)) = v;
                }
            }
        } else {
            const char* half = lds + (bat & 1) * (SCAN_S * 512);
            __hip_bfloat16* hq = hp + (long)(bat * SCAN_S) * hstep;
#pragma unroll 8
            for (int s2 = 0; s2 < SCAN_S; ++s2) {
                const uint2 u = *(const uint2*)(half + s2 * 512 + (lane << 3));
                float u0, u1s, u2s, u3;
                {
                    unsigned a0 = u.x << 16, a1 = u.x & 0xffff0000u;
                    unsigned a2 = u.y << 16, a3 = u.y & 0xffff0000u;
                    __builtin_memcpy(&u0, &a0, 4); __builtin_memcpy(&u1s, &a1, 4);
                    __builtin_memcpy(&u2s, &a2, 4); __builtin_memcpy(&u3, &a3, 4);
                }
                const float ef = __builtin_amdgcn_exp2f(__builtin_fmaf(nvf, c, u1s));
                const float er = __builtin_amdgcn_exp2f(__builtin_fmaf(nvr, c, u2s));
                const float f  = __builtin_amdgcn_rcpf(1.0f + ef);
                const float r  = __builtin_amdgcn_rcpf(1.0f + er);
                const float c2 = __builtin_fmaf(f, c - u0, u0);
                const float hv = __builtin_fmaf(r, c2 - u3, u3);
                c = c2;
                hq[(long)s2 * hstep] = __float2bfloat16(hv);
            }
        }
        __syncthreads();
    }
}

// ---------------------------------------------------------------------------
// MFMA logits + log_softmax. Block = 256 threads, 128 rows. K=256, N=32.
__global__ __launch_bounds__(256) void logits_mfma(
    const __hip_bfloat16* __restrict__ fc,    // (M_ROWS,256) bf16
    const __hip_bfloat16* __restrict__ lpwb,  // (32,256) bf16, padded
    const float* __restrict__ lpb,            // (21,)
    float* __restrict__ out)
{
    __shared__ __align__(16) char smb[25088];
    const int tid  = threadIdx.x;
    const int lane = tid & 63;
    const int wave = tid >> 6;
    const long m0  = (long)blockIdx.x * 128;

    for (int idx = tid; idx < 32 * 32; idx += 256) {
        const int rw = idx >> 5, sl = idx & 31;
        *(bf16x8*)(smb + rw * 528 + sl * 16) =
            *(const bf16x8*)(lpwb + rw * 256 + sl * 8);
    }

    const int ldrow = lane >> 2;
    const int ldq   = lane & 3;
    const int gq    = ldq ^ ((ldrow >> 1) & 3);
    const int gkoff = gq * 8;

    const int fr = lane & 15;
    const int kq = lane >> 4;
    const int sw = (kq ^ ((fr >> 1) & 3)) * 16;

    f32x4 acc[2][2] = {};
    for (int kc = 0; kc < 8; ++kc) {
        __syncthreads();
#pragma unroll
        for (int i = 0; i < 2; ++i) {
            const int rc = wave * 2 + i;
            gload_lds16(fc + (m0 + rc * 16 + ldrow) * 256 + kc * 32 + gkoff,
                        smb + 16896 + rc * 1024);
        }
        __syncthreads();
        bf16x8 af[2], bfv[2];
#pragma unroll
        for (int i = 0; i < 2; ++i)
            af[i] = *(const bf16x8*)(smb + 16896 + (wave * 2 + i) * 1024 + fr * 64 + sw);
#pragma unroll
        for (int j = 0; j < 2; ++j)
            bfv[j] = *(const bf16x8*)(smb + (j * 16 + fr) * 528 + kc * 64 + kq * 16);
#pragma unroll
        for (int i = 0; i < 2; ++i)
#pragma unroll
            for (int j = 0; j < 2; ++j)
                acc[i][j] = __builtin_amdgcn_mfma_f32_16x16x32_bf16(
                    af[i], bfv[j], acc[i][j], 0, 0, 0);
    }

    __syncthreads();
    float* smC = (float*)smb;                  // stride 36 f32
    const int col_l = lane & 15;
    const int row_l = (lane >> 4) * 4;
#pragma unroll
    for (int j = 0; j < 2; ++j) {
        const int gc = j * 16 + col_l;
        const float bv = (gc < AA_DIM) ? lpb[gc] : 0.0f;
#pragma unroll
        for (int i = 0; i < 2; ++i)
#pragma unroll
            for (int r = 0; r < 4; ++r)
                smC[(wave * 32 + i * 16 + row_l + r) * 36 + gc] = acc[i][j][r] + bv;
    }
    __syncthreads();
    if (tid < 128) {
        const float* rowp = smC + tid * 36;
        float m = rowp[0];
#pragma unroll
        for (int a = 1; a < AA_DIM; ++a) m = fmaxf(m, rowp[a]);
        float s = 0.0f;
#pragma unroll
        for (int a = 0; a < AA_DIM; ++a) s += __expf(rowp[a] - m);
        const float lse = __logf(s) + m;
        float* op = out + (m0 + tid) * AA_DIM;
#pragma unroll
        for (int a = 0; a < AA_DIM; ++a) op[a] = rowp[a] - lse;
    }
}

// ---------------------------------------------------------------------------
extern "C" void kernel_launch(void* const* d_in, const int* in_sizes, int n_in,
                              void* d_out, int out_size, void* d_ws, size_t ws_size,
                              hipStream_t stream)
{
    const float* x     = (const float*)d_in[0];
    const float* w_l0  = (const float*)d_in[2];
    const float* wc_l0 = (const float*)d_in[3];
    const float* b_l0  = (const float*)d_in[4];
    const float* w_l1  = (const float*)d_in[5];
    const float* wc_l1 = (const float*)d_in[6];
    const float* b_l1  = (const float*)d_in[7];
    const float* fc1_w = (const float*)d_in[8];
    const float* fc1_b = (const float*)d_in[9];
    const float* lp_w  = (const float*)d_in[10];
    const float* lp_b  = (const float*)d_in[11];
    float* out = (float*)d_out;

    char* ws = (char*)d_ws;
    __hip_bfloat16* U      = (__hip_bfloat16*)(ws);              // 134,217,728 B (U2 layout)
    __hip_bfloat16* h0b    = (__hip_bfloat16*)(ws + 134217728);  //  33,554,432
    __hip_bfloat16* h1b    = (__hip_bfloat16*)(ws + 167772160);  //  33,554,432
    __hip_bfloat16* xb     = (__hip_bfloat16*)(ws + 201326592);  //  16,777,216
    __hip_bfloat16* fcob   = xb;                                 //  alias after GEMM0
    __hip_bfloat16* w0t    = (__hip_bfloat16*)(ws + 218103808);  //  (2048,256)
    __hip_bfloat16* w1t    = (__hip_bfloat16*)(ws + 219152384);  //  (2048,512)
    __hip_bfloat16* fc1wb  = (__hip_bfloat16*)(ws + 221249536);  //  (256,512)
    __hip_bfloat16* lpwb   = (__hip_bfloat16*)(ws + 221511680);  //  (32,256)
    float* sc0 = (float*)(ws + 221528064);
    float* bs0 = (float*)(ws + 221536256);
    float* sc1 = (float*)(ws + 221544448);
    float* bs1 = (float*)(ws + 221552640);

    cvt_all<<<(CVT_TOT + 255) / 256, 256, 0, stream>>>(
        x, w_l0, w_l1, fc1_w, lp_w, b_l0, b_l1,
        xb, w0t, w1t, fc1wb, lpwb, sc0, bs0, sc1, bs1);

    // U-GEMMs write U2 layout; grid = MB*NB (1-D), MB=256, NB=16, nbShift=4
    gemm_bf16<1><<<4096, 256, 0, stream>>>(
        xb, w0t, bs0, sc0, U, M_ROWS, 2048, DIN_DIM, 4);
    sru_scan<<<256, 256, 0, stream>>>(U, wc_l0, h0b);
    gemm_bf16<1><<<4096, 256, 0, stream>>>(
        h0b, w1t, bs1, sc1, U, M_ROWS, 2048, 512, 4);
    sru_scan<<<256, 256, 0, stream>>>(U, wc_l1, h1b);
    // fc GEMM: plain layout, NB=2 -> 512 blocks, nbShift=1
    gemm_bf16<0><<<512, 256, 0, stream>>>(
        h1b, fc1wb, fc1_b, nullptr, fcob, M_ROWS, 256, 512, 1);
    logits_mfma<<<M_ROWS / 128, 256, 0, stream>>>(fcob, lpwb, lp_b, out);
}

// Round 11
// 422.546 us; speedup vs baseline: 1.1448x; 1.1448x over previous
//
#include <hip/hip_runtime.h>
#include <hip/hip_bf16.h>

// Problem dims (fixed): T=1024, B=32, DIN=256, H=256, AA=21, L=2
#define T_DIM 1024
#define B_DIM 32
#define DIN_DIM 256
#define H_DIM 256
#define AA_DIM 21
#define M_ROWS (B_DIM * T_DIM)   // 32768 rows, row index = b*T + t everywhere

typedef __attribute__((ext_vector_type(8))) short bf16x8;   // 8 bf16 = 4 VGPRs
typedef __attribute__((ext_vector_type(4))) float f32x4;

typedef __attribute__((address_space(3))) void lds_void;
typedef const __attribute__((address_space(1))) void glb_void;

#define LOG2E_F 1.44269504088896340736f

__device__ __forceinline__ void gload_lds16(const void* g, void* l) {
    // per-lane global gather -> LDS at (wave-uniform base + lane*16), async
    __builtin_amdgcn_global_load_lds((glb_void*)g, (lds_void*)l, 16, 0, 0);
}

__device__ __forceinline__ float b2f(unsigned short v) {
    unsigned u = ((unsigned)v) << 16;
    float f;
    __builtin_memcpy(&f, &u, 4);
    return f;
}

__device__ __forceinline__ unsigned short f2bu(float f) {
    __hip_bfloat16 h = __float2bfloat16(f);
    unsigned short u;
    __builtin_memcpy(&u, &h, 2);
    return u;
}

// ---------------------------------------------------------------------------
// All weight/input converts fused into ONE dispatch (vectorized bulk paths).
// seg0: x -> xb bf16 (float4/thread)   seg1: w_l0 -> w0t (2048,256) interleaved
// seg2: w_l1 -> w1t (2048,512)         seg3: fc1_w -> fc1wb
// seg4: lp_w -> lpwb (32,256) padded
#define CVT_V0 2097152            // 8388608 / 4
#define CVT_N1 524288
#define CVT_N2 1048576
#define CVT_V3 32768              // 131072 / 4
#define CVT_N4 8192
#define CVT_TOT (CVT_V0 + CVT_N1 + CVT_N2 + CVT_V3 + CVT_N4)
__global__ __launch_bounds__(256) void cvt_all(
    const float* __restrict__ x,  const float* __restrict__ w0,
    const float* __restrict__ w1, const float* __restrict__ fcw,
    const float* __restrict__ lpw,
    __hip_bfloat16* __restrict__ xb,  __hip_bfloat16* __restrict__ w0t,
    __hip_bfloat16* __restrict__ w1t, __hip_bfloat16* __restrict__ fcwb,
    __hip_bfloat16* __restrict__ lpwb)
{
    int i = blockIdx.x * 256 + threadIdx.x;
    if (i < CVT_V0) {
        float4 v = ((const float4*)x)[i];
        ushort4 o = { f2bu(v.x), f2bu(v.y), f2bu(v.z), f2bu(v.w) };
        ((ushort4*)xb)[i] = o;
        return;
    }
    i -= CVT_V0;
    if (i < CVT_N1) {   // w0t, K=256; input flat ((kk*2+dir)*4+k)*H + h
        int kk = i >> 11, rem = i & 2047;
        int dir = rem >> 10, k = (rem >> 8) & 3, h = rem & 255;
        w0t[(long)(dir * 1024 + h * 4 + k) * 256 + kk] = __float2bfloat16(w0[i]);
        return;
    }
    i -= CVT_N1;
    if (i < CVT_N2) {   // w1t, K=512
        int kk = i >> 11, rem = i & 2047;
        int dir = rem >> 10, k = (rem >> 8) & 3, h = rem & 255;
        w1t[(long)(dir * 1024 + h * 4 + k) * 512 + kk] = __float2bfloat16(w1[i]);
        return;
    }
    i -= CVT_N2;
    if (i < CVT_V3) {
        float4 v = ((const float4*)fcw)[i];
        ushort4 o = { f2bu(v.x), f2bu(v.y), f2bu(v.z), f2bu(v.w) };
        ((ushort4*)fcwb)[i] = o;
        return;
    }
    i -= CVT_V3;
    if (i < CVT_N4) {   // lpwb (32,256), zero-padded past row 20
        int n = i >> 8, k = i & 255;
        lpwb[i] = __float2bfloat16(n < AA_DIM ? lpw[n * 256 + k] : 0.0f);
    }
}

// ---------------------------------------------------------------------------
// bf16 GEMM: C = A*Bt^T (+bias), 128x128 tile, BK=64, XCD-aware 1-D grid
// swizzle, swizzled global_load_lds staging (0 conflicts), two-pass stride-132
// LDS epilogue (0 conflicts, full-line stores).
// U2OUT=1: scan-friendly layout [beta=b*8+dir*4+hg][t][64h x 4k] (beta slice =
// contiguous 512 KB; per-thread store stays 32B contiguous).
template<int U2OUT>
__global__ __launch_bounds__(256) void gemm_bf16(
    const __hip_bfloat16* __restrict__ A,
    const __hip_bfloat16* __restrict__ Bt,
    const float* __restrict__ bias,    // len N or nullptr
    __hip_bfloat16* __restrict__ C,
    int M, int N, int K, int nbShift)
{
    __shared__ __align__(16) char smb[32768];

    const int tid  = threadIdx.x;
    const int lane = tid & 63;
    const int wave = tid >> 6;
    const int wm = wave & 1;
    const int wn = wave >> 1;

    const int L   = blockIdx.x;
    const int s   = L >> 3;
    const int nb  = s & ((1 << nbShift) - 1);
    const int mb  = ((s >> nbShift) << 3) + (L & 7);
    const long n0 = (long)nb * 128;
    const long m0 = (long)mb * 128;

    f32x4 acc[4][4] = {};

    const int ldrow = lane >> 2;
    const int ldq   = lane & 3;
    const int gq    = ldq ^ ((ldrow >> 1) & 3);
    const int gkoff = gq * 8;

    const int fr = lane & 15;
    const int kq = lane >> 4;
    const int sw = (kq ^ ((fr >> 1) & 3)) * 16;

    for (int kb = 0; kb < K; kb += 64) {
        __syncthreads();
#pragma unroll
        for (int i = 0; i < 4; ++i) {
            const int cid = wave * 4 + i;
            const int rc  = cid >> 1;
            const int kh  = cid & 1;
            const long row = rc * 16 + ldrow;
            const int koff = kb + kh * 32 + gkoff;
            gload_lds16(A  + (m0 + row) * (long)K + koff,
                        smb + rc * 2048 + kh * 1024);
            gload_lds16(Bt + (n0 + row) * (long)K + koff,
                        smb + 16384 + rc * 2048 + kh * 1024);
        }
        __syncthreads();

#pragma unroll
        for (int ss = 0; ss < 2; ++ss) {
            bf16x8 af[4], bfv[4];
#pragma unroll
            for (int i = 0; i < 4; ++i) {
                af[i]  = *(const bf16x8*)(smb + (wm * 4 + i) * 2048 + ss * 1024 + fr * 64 + sw);
                bfv[i] = *(const bf16x8*)(smb + 16384 + (wn * 4 + i) * 2048 + ss * 1024 + fr * 64 + sw);
            }
#pragma unroll
            for (int i = 0; i < 4; ++i)
#pragma unroll
                for (int j = 0; j < 4; ++j)
                    acc[i][j] = __builtin_amdgcn_mfma_f32_16x16x32_bf16(
                        af[i], bfv[j], acc[i][j], 0, 0, 0);
        }
    }

    // ---- epilogue: C/D layout col=lane&15, row=(lane>>4)*4+reg ----
    const int col_l = lane & 15;
    const int row_l = (lane >> 4) * 4;
    __hip_bfloat16* smC = (__hip_bfloat16*)smb;   // stride 132 bf16
#pragma unroll
    for (int p = 0; p < 2; ++p) {
        __syncthreads();
        if (wm == p) {
#pragma unroll
            for (int j = 0; j < 4; ++j) {
                const long gc = n0 + wn * 64 + j * 16 + col_l;
                const float bv = bias ? bias[gc] : 0.0f;
#pragma unroll
                for (int i = 0; i < 4; ++i)
#pragma unroll
                    for (int r = 0; r < 4; ++r)
                        smC[(i * 16 + row_l + r) * 132 + wn * 64 + j * 16 + col_l] =
                            __float2bfloat16(acc[i][j][r] + bv);
            }
        }
        __syncthreads();
        const int cb = (tid & 7) * 16;      // col start (elems), 32B/thread
#pragma unroll
        for (int s2 = 0; s2 < 2; ++s2) {
            const int rr = s2 * 32 + (tid >> 3);
            const long gr = m0 + p * 64 + rr;
            bf16x8 v0 = *(const bf16x8*)(smC + rr * 132 + cb);
            bf16x8 v1 = *(const bf16x8*)(smC + rr * 132 + cb + 8);
            if (U2OUT) {
                const int bI  = (int)(gr >> 10);
                const int t   = (int)(gr & 1023);
                const long gc0 = n0 + cb;
                const int dir = (int)(gc0 >> 10);
                const int hg  = ((int)gc0 >> 8) & 3;
                const int beta = bI * 8 + dir * 4 + hg;
                const long base = ((long)beta * 1024 + t) * 256 + (gc0 & 255);
                *(bf16x8*)(C + base)     = v0;
                *(bf16x8*)(C + base + 8) = v1;
            } else {
                *(bf16x8*)(C + gr * (long)N + n0 + cb)     = v0;
                *(bf16x8*)(C + gr * (long)N + n0 + cb + 8) = v1;
            }
        }
    }
}

// ---------------------------------------------------------------------------
// SRU scan, producer-consumer with ASYNC direct-to-LDS staging.
// 256 blocks x 256 threads; block beta owns 64 recurrences (b=beta>>3,
// dir=(beta>>2)&1, hg=beta&3; h=hg*64+lane). U2 slice for beta = contiguous
// 512 KB [t][64h x 4k]. Waves 1-3 issue global_load_lds (fire-and-forget; no
// register round-trip, no per-iteration dependency) into a double-buffered
// 64-step LDS ring; __syncthreads' vmcnt(0) drain is the only wait. Wave 0
// consumes from LDS (~30 cyc/step serial chain). LDS pair mapping: lanes 0-31
// stage step 2p, lanes 32-63 step 2p+1 (base + lane*16 constraint satisfied).
#define SCAN_S 64
#define SCAN_NB (T_DIM / SCAN_S)   // 16
__global__ __launch_bounds__(256) void sru_scan(
    const __hip_bfloat16* __restrict__ U2,
    const float* __restrict__ wc,    // (2,2,H)
    const float* __restrict__ bias,  // (2,2,H)
    __hip_bfloat16* __restrict__ hout)
{
    __shared__ __align__(16) char lds[2 * SCAN_S * 512];   // 65536 B
    const int tid  = threadIdx.x;
    const int wave = tid >> 6;
    const int lane = tid & 63;
    const int beta = blockIdx.x;
    const int b    = beta >> 3;
    const int dir  = (beta >> 2) & 1;
    const int hg   = beta & 3;
    const int h    = hg * 64 + lane;

    const char* gslice = (const char*)U2 + (size_t)beta * (1024 * 512);

    const float nvf = -LOG2E_F * wc[(dir * 2 + 0) * H_DIM + h];
    const float nvr = -LOG2E_F * wc[(dir * 2 + 1) * H_DIM + h];
    const float nbf = -LOG2E_F * bias[(dir * 2 + 0) * H_DIM + h];
    const float nbr = -LOG2E_F * bias[(dir * 2 + 1) * H_DIM + h];
    __hip_bfloat16* hp = hout + ((long)(b * 1024 + (dir ? 1023 : 0))) * 512 + dir * 256 + h;
    const long hstep = dir ? -512L : 512L;
    float c = 0.0f;

    // lane-side producer addressing: pair p stages steps (2p, 2p+1)
    const int plane = lane & 31;            // byte slot within a step

    // prologue: producers async-fill half 0 with batch 0 (tb = 0)
    if (wave > 0) {
        for (int p = wave - 1; p < SCAN_S / 2; p += 3) {
            const int sl = 2 * p + (lane >> 5);            // step in batch
            const int t  = dir ? (1023 - sl) : sl;
            gload_lds16(gslice + (size_t)t * 512 + plane * 16,
                        lds + p * 1024);
        }
    }
    __syncthreads();   // vmcnt(0) drain: batch 0 resident

    for (int bat = 0; bat < SCAN_NB; ++bat) {
        if (wave > 0) {
            if (bat + 1 < SCAN_NB) {
                char* half = lds + ((bat + 1) & 1) * (SCAN_S * 512);
                const int tb = (bat + 1) * SCAN_S;
                for (int p = wave - 1; p < SCAN_S / 2; p += 3) {
                    const int sl = tb + 2 * p + (lane >> 5);
                    const int t  = dir ? (1023 - sl) : sl;
                    gload_lds16(gslice + (size_t)t * 512 + plane * 16,
                                half + p * 1024);
                }
            }
        } else {
            const char* half = lds + (bat & 1) * (SCAN_S * 512);
            __hip_bfloat16* hq = hp + (long)(bat * SCAN_S) * hstep;
#pragma unroll 8
            for (int s2 = 0; s2 < SCAN_S; ++s2) {
                const uint2 u = *(const uint2*)(half + s2 * 512 + (lane << 3));
                float u0, u1, u2, u3;
                {
                    unsigned a0 = u.x << 16, a1 = u.x & 0xffff0000u;
                    unsigned a2 = u.y << 16, a3 = u.y & 0xffff0000u;
                    __builtin_memcpy(&u0, &a0, 4); __builtin_memcpy(&u1, &a1, 4);
                    __builtin_memcpy(&u2, &a2, 4); __builtin_memcpy(&u3, &a3, 4);
                }
                // off-chain: fold -log2e*(u+b) for both gates
                const float nf0 = __builtin_fmaf(-LOG2E_F, u1, nbf);
                const float nr0 = __builtin_fmaf(-LOG2E_F, u2, nbr);
                // serial chain on c
                const float ef = __builtin_amdgcn_exp2f(__builtin_fmaf(nvf, c, nf0));
                const float er = __builtin_amdgcn_exp2f(__builtin_fmaf(nvr, c, nr0));
                const float f  = __builtin_amdgcn_rcpf(1.0f + ef);
                const float r  = __builtin_amdgcn_rcpf(1.0f + er);
                const float c2 = __builtin_fmaf(f, c - u0, u0);
                const float hv = __builtin_fmaf(r, c2 - u3, u3);
                c = c2;
                hq[(long)s2 * hstep] = __float2bfloat16(hv);
            }
        }
        __syncthreads();   // drains producers' vmcnt + protects ring halves
    }
}

// ---------------------------------------------------------------------------
// MFMA logits + log_softmax. Block = 256 threads, 128 rows. K=256, N=32.
__global__ __launch_bounds__(256) void logits_mfma(
    const __hip_bfloat16* __restrict__ fc,    // (M_ROWS,256) bf16
    const __hip_bfloat16* __restrict__ lpwb,  // (32,256) bf16, padded
    const float* __restrict__ lpb,            // (21,)
    float* __restrict__ out)
{
    __shared__ __align__(16) char smb[25088];
    const int tid  = threadIdx.x;
    const int lane = tid & 63;
    const int wave = tid >> 6;
    const long m0  = (long)blockIdx.x * 128;

    for (int idx = tid; idx < 32 * 32; idx += 256) {
        const int rw = idx >> 5, sl = idx & 31;
        *(bf16x8*)(smb + rw * 528 + sl * 16) =
            *(const bf16x8*)(lpwb + rw * 256 + sl * 8);
    }

    const int ldrow = lane >> 2;
    const int ldq   = lane & 3;
    const int gq    = ldq ^ ((ldrow >> 1) & 3);
    const int gkoff = gq * 8;

    const int fr = lane & 15;
    const int kq = lane >> 4;
    const int sw = (kq ^ ((fr >> 1) & 3)) * 16;

    f32x4 acc[2][2] = {};
    for (int kc = 0; kc < 8; ++kc) {
        __syncthreads();
#pragma unroll
        for (int i = 0; i < 2; ++i) {
            const int rc = wave * 2 + i;
            gload_lds16(fc + (m0 + rc * 16 + ldrow) * 256 + kc * 32 + gkoff,
                        smb + 16896 + rc * 1024);
        }
        __syncthreads();
        bf16x8 af[2], bfv[2];
#pragma unroll
        for (int i = 0; i < 2; ++i)
            af[i] = *(const bf16x8*)(smb + 16896 + (wave * 2 + i) * 1024 + fr * 64 + sw);
#pragma unroll
        for (int j = 0; j < 2; ++j)
            bfv[j] = *(const bf16x8*)(smb + (j * 16 + fr) * 528 + kc * 64 + kq * 16);
#pragma unroll
        for (int i = 0; i < 2; ++i)
#pragma unroll
            for (int j = 0; j < 2; ++j)
                acc[i][j] = __builtin_amdgcn_mfma_f32_16x16x32_bf16(
                    af[i], bfv[j], acc[i][j], 0, 0, 0);
    }

    __syncthreads();
    float* smC = (float*)smb;                  // stride 36 f32
    const int col_l = lane & 15;
    const int row_l = (lane >> 4) * 4;
#pragma unroll
    for (int j = 0; j < 2; ++j) {
        const int gc = j * 16 + col_l;
        const float bv = (gc < AA_DIM) ? lpb[gc] : 0.0f;
#pragma unroll
        for (int i = 0; i < 2; ++i)
#pragma unroll
            for (int r = 0; r < 4; ++r)
                smC[(wave * 32 + i * 16 + row_l + r) * 36 + gc] = acc[i][j][r] + bv;
    }
    __syncthreads();
    if (tid < 128) {
        const float* rowp = smC + tid * 36;
        float m = rowp[0];
#pragma unroll
        for (int a = 1; a < AA_DIM; ++a) m = fmaxf(m, rowp[a]);
        float s = 0.0f;
#pragma unroll
        for (int a = 0; a < AA_DIM; ++a) s += __expf(rowp[a] - m);
        const float lse = __logf(s) + m;
        float* op = out + (m0 + tid) * AA_DIM;
#pragma unroll
        for (int a = 0; a < AA_DIM; ++a) op[a] = rowp[a] - lse;
    }
}

// ---------------------------------------------------------------------------
extern "C" void kernel_launch(void* const* d_in, const int* in_sizes, int n_in,
                              void* d_out, int out_size, void* d_ws, size_t ws_size,
                              hipStream_t stream)
{
    const float* x     = (const float*)d_in[0];
    const float* w_l0  = (const float*)d_in[2];
    const float* wc_l0 = (const float*)d_in[3];
    const float* b_l0  = (const float*)d_in[4];
    const float* w_l1  = (const float*)d_in[5];
    const float* wc_l1 = (const float*)d_in[6];
    const float* b_l1  = (const float*)d_in[7];
    const float* fc1_w = (const float*)d_in[8];
    const float* fc1_b = (const float*)d_in[9];
    const float* lp_w  = (const float*)d_in[10];
    const float* lp_b  = (const float*)d_in[11];
    float* out = (float*)d_out;

    char* ws = (char*)d_ws;
    __hip_bfloat16* U      = (__hip_bfloat16*)(ws);              // 134,217,728 B (U2 layout)
    __hip_bfloat16* h0b    = (__hip_bfloat16*)(ws + 134217728);  //  33,554,432
    __hip_bfloat16* h1b    = (__hip_bfloat16*)(ws + 167772160);  //  33,554,432
    __hip_bfloat16* xb     = (__hip_bfloat16*)(ws + 201326592);  //  16,777,216
    __hip_bfloat16* fcob   = xb;                                 //  alias after GEMM0
    __hip_bfloat16* w0t    = (__hip_bfloat16*)(ws + 218103808);  //  (2048,256)
    __hip_bfloat16* w1t    = (__hip_bfloat16*)(ws + 219152384);  //  (2048,512)
    __hip_bfloat16* fc1wb  = (__hip_bfloat16*)(ws + 221249536);  //  (256,512)
    __hip_bfloat16* lpwb   = (__hip_bfloat16*)(ws + 221511680);  //  (32,256)

    cvt_all<<<(CVT_TOT + 255) / 256, 256, 0, stream>>>(
        x, w_l0, w_l1, fc1_w, lp_w, xb, w0t, w1t, fc1wb, lpwb);

    // U-GEMMs write U2 layout; grid = MB*NB (1-D), MB=256, NB=16, nbShift=4
    gemm_bf16<1><<<4096, 256, 0, stream>>>(
        xb, w0t, nullptr, U, M_ROWS, 2048, DIN_DIM, 4);
    sru_scan<<<256, 256, 0, stream>>>(U, wc_l0, b_l0, h0b);
    gemm_bf16<1><<<4096, 256, 0, stream>>>(
        h0b, w1t, nullptr, U, M_ROWS, 2048, 512, 4);
    sru_scan<<<256, 256, 0, stream>>>(U, wc_l1, b_l1, h1b);
    // fc GEMM: plain layout, NB=2 -> 512 blocks, nbShift=1
    gemm_bf16<0><<<512, 256, 0, stream>>>(
        h1b, fc1wb, fc1_b, fcob, M_ROWS, 256, 512, 1);
    logits_mfma<<<M_ROWS / 128, 256, 0, stream>>>(fcob, lpwb, lp_b, out);
}

// Round 12
// 383.231 us; speedup vs baseline: 1.2622x; 1.1026x over previous
//
#include <hip/hip_runtime.h>
#include <hip/hip_bf16.h>

// Problem dims (fixed): T=1024, B=32, DIN=256, H=256, AA=21, L=2
#define T_DIM 1024
#define B_DIM 32
#define DIN_DIM 256
#define H_DIM 256
#define AA_DIM 21
#define M_ROWS (B_DIM * T_DIM)   // 32768 rows, row index = b*T + t everywhere

typedef __attribute__((ext_vector_type(8))) short bf16x8;   // 8 bf16 = 4 VGPRs
typedef __attribute__((ext_vector_type(4))) float f32x4;

typedef __attribute__((address_space(3))) void lds_void;
typedef const __attribute__((address_space(1))) void glb_void;

#define LOG2E_F 1.44269504088896340736f

__device__ __forceinline__ void gload_lds16(const void* g, void* l) {
    // per-lane global gather -> LDS at (wave-uniform base + lane*16), async
    __builtin_amdgcn_global_load_lds((glb_void*)g, (lds_void*)l, 16, 0, 0);
}

__device__ __forceinline__ float b2f(unsigned short v) {
    unsigned u = ((unsigned)v) << 16;
    float f;
    __builtin_memcpy(&f, &u, 4);
    return f;
}

__device__ __forceinline__ unsigned short f2bu(float f) {
    __hip_bfloat16 h = __float2bfloat16(f);
    unsigned short u;
    __builtin_memcpy(&u, &h, 2);
    return u;
}

// ---------------------------------------------------------------------------
// All weight/input converts fused into ONE dispatch (vectorized bulk paths).
#define CVT_V0 2097152            // 8388608 / 4
#define CVT_N1 524288
#define CVT_N2 1048576
#define CVT_V3 32768              // 131072 / 4
#define CVT_N4 8192
#define CVT_TOT (CVT_V0 + CVT_N1 + CVT_N2 + CVT_V3 + CVT_N4)
__global__ __launch_bounds__(256) void cvt_all(
    const float* __restrict__ x,  const float* __restrict__ w0,
    const float* __restrict__ w1, const float* __restrict__ fcw,
    const float* __restrict__ lpw,
    __hip_bfloat16* __restrict__ xb,  __hip_bfloat16* __restrict__ w0t,
    __hip_bfloat16* __restrict__ w1t, __hip_bfloat16* __restrict__ fcwb,
    __hip_bfloat16* __restrict__ lpwb)
{
    int i = blockIdx.x * 256 + threadIdx.x;
    if (i < CVT_V0) {
        float4 v = ((const float4*)x)[i];
        ushort4 o = { f2bu(v.x), f2bu(v.y), f2bu(v.z), f2bu(v.w) };
        ((ushort4*)xb)[i] = o;
        return;
    }
    i -= CVT_V0;
    if (i < CVT_N1) {   // w0t, K=256; input flat ((kk*2+dir)*4+k)*H + h
        int kk = i >> 11, rem = i & 2047;
        int dir = rem >> 10, k = (rem >> 8) & 3, h = rem & 255;
        w0t[(long)(dir * 1024 + h * 4 + k) * 256 + kk] = __float2bfloat16(w0[i]);
        return;
    }
    i -= CVT_N1;
    if (i < CVT_N2) {   // w1t, K=512
        int kk = i >> 11, rem = i & 2047;
        int dir = rem >> 10, k = (rem >> 8) & 3, h = rem & 255;
        w1t[(long)(dir * 1024 + h * 4 + k) * 512 + kk] = __float2bfloat16(w1[i]);
        return;
    }
    i -= CVT_N2;
    if (i < CVT_V3) {
        float4 v = ((const float4*)fcw)[i];
        ushort4 o = { f2bu(v.x), f2bu(v.y), f2bu(v.z), f2bu(v.w) };
        ((ushort4*)fcwb)[i] = o;
        return;
    }
    i -= CVT_V3;
    if (i < CVT_N4) {   // lpwb (32,256), zero-padded past row 20
        int n = i >> 8, k = i & 255;
        lpwb[i] = __float2bfloat16(n < AA_DIM ? lpw[n * 256 + k] : 0.0f);
    }
}

// ---------------------------------------------------------------------------
// bf16 GEMM: C = A*Bt^T (+bias), 128x128 tile, BK=64, XCD-aware 1-D grid
// swizzle, swizzled global_load_lds staging (0 conflicts), two-pass stride-132
// LDS epilogue (0 conflicts, full-line stores).
// U2OUT=1: scan-friendly layout [beta=b*8+dir*4+hg][t][64h x 4k].
template<int U2OUT>
__global__ __launch_bounds__(256) void gemm_bf16(
    const __hip_bfloat16* __restrict__ A,
    const __hip_bfloat16* __restrict__ Bt,
    const float* __restrict__ bias,    // len N or nullptr
    __hip_bfloat16* __restrict__ C,
    int M, int N, int K, int nbShift)
{
    __shared__ __align__(16) char smb[32768];

    const int tid  = threadIdx.x;
    const int lane = tid & 63;
    const int wave = tid >> 6;
    const int wm = wave & 1;
    const int wn = wave >> 1;

    const int L   = blockIdx.x;
    const int s   = L >> 3;
    const int nb  = s & ((1 << nbShift) - 1);
    const int mb  = ((s >> nbShift) << 3) + (L & 7);
    const long n0 = (long)nb * 128;
    const long m0 = (long)mb * 128;

    f32x4 acc[4][4] = {};

    const int ldrow = lane >> 2;
    const int ldq   = lane & 3;
    const int gq    = ldq ^ ((ldrow >> 1) & 3);
    const int gkoff = gq * 8;

    const int fr = lane & 15;
    const int kq = lane >> 4;
    const int sw = (kq ^ ((fr >> 1) & 3)) * 16;

    for (int kb = 0; kb < K; kb += 64) {
        __syncthreads();
#pragma unroll
        for (int i = 0; i < 4; ++i) {
            const int cid = wave * 4 + i;
            const int rc  = cid >> 1;
            const int kh  = cid & 1;
            const long row = rc * 16 + ldrow;
            const int koff = kb + kh * 32 + gkoff;
            gload_lds16(A  + (m0 + row) * (long)K + koff,
                        smb + rc * 2048 + kh * 1024);
            gload_lds16(Bt + (n0 + row) * (long)K + koff,
                        smb + 16384 + rc * 2048 + kh * 1024);
        }
        __syncthreads();

#pragma unroll
        for (int ss = 0; ss < 2; ++ss) {
            bf16x8 af[4], bfv[4];
#pragma unroll
            for (int i = 0; i < 4; ++i) {
                af[i]  = *(const bf16x8*)(smb + (wm * 4 + i) * 2048 + ss * 1024 + fr * 64 + sw);
                bfv[i] = *(const bf16x8*)(smb + 16384 + (wn * 4 + i) * 2048 + ss * 1024 + fr * 64 + sw);
            }
#pragma unroll
            for (int i = 0; i < 4; ++i)
#pragma unroll
                for (int j = 0; j < 4; ++j)
                    acc[i][j] = __builtin_amdgcn_mfma_f32_16x16x32_bf16(
                        af[i], bfv[j], acc[i][j], 0, 0, 0);
        }
    }

    // ---- epilogue: C/D layout col=lane&15, row=(lane>>4)*4+reg ----
    const int col_l = lane & 15;
    const int row_l = (lane >> 4) * 4;
    __hip_bfloat16* smC = (__hip_bfloat16*)smb;   // stride 132 bf16
#pragma unroll
    for (int p = 0; p < 2; ++p) {
        __syncthreads();
        if (wm == p) {
#pragma unroll
            for (int j = 0; j < 4; ++j) {
                const long gc = n0 + wn * 64 + j * 16 + col_l;
                const float bv = bias ? bias[gc] : 0.0f;
#pragma unroll
                for (int i = 0; i < 4; ++i)
#pragma unroll
                    for (int r = 0; r < 4; ++r)
                        smC[(i * 16 + row_l + r) * 132 + wn * 64 + j * 16 + col_l] =
                            __float2bfloat16(acc[i][j][r] + bv);
            }
        }
        __syncthreads();
        const int cb = (tid & 7) * 16;      // col start (elems), 32B/thread
#pragma unroll
        for (int s2 = 0; s2 < 2; ++s2) {
            const int rr = s2 * 32 + (tid >> 3);
            const long gr = m0 + p * 64 + rr;
            bf16x8 v0 = *(const bf16x8*)(smC + rr * 132 + cb);
            bf16x8 v1 = *(const bf16x8*)(smC + rr * 132 + cb + 8);
            if (U2OUT) {
                const int bI  = (int)(gr >> 10);
                const int t   = (int)(gr & 1023);
                const long gc0 = n0 + cb;
                const int dir = (int)(gc0 >> 10);
                const int hg  = ((int)gc0 >> 8) & 3;
                const int beta = bI * 8 + dir * 4 + hg;
                const long base = ((long)beta * 1024 + t) * 256 + (gc0 & 255);
                *(bf16x8*)(C + base)     = v0;
                *(bf16x8*)(C + base + 8) = v1;
            } else {
                *(bf16x8*)(C + gr * (long)N + n0 + cb)     = v0;
                *(bf16x8*)(C + gr * (long)N + n0 + cb + 8) = v1;
            }
        }
    }
}

// ---------------------------------------------------------------------------
// SRU scan, producer-consumer, async direct-to-LDS staging + GROUPED consumer
// reads. 256 blocks x 256 threads; block beta owns 64 recurrences. Waves 1-3
// stage batch bat+1 via global_load_lds into the other ring half. Wave 0
// consumes batch bat with register double-buffered groups of 16 ds_read_b64s
// issued ahead of the 16-step serial chain (GEMM-style straight-line grouping
// -> compiler emits progressive lgkmcnt waits, LDS latency hidden).
#define SCAN_S 64
#define SCAN_NB (T_DIM / SCAN_S)   // 16
#define GRP 16

__device__ __forceinline__ float scan_step(
    uint2 u, float c, float nvf, float nvr, float nbf, float nbr,
    __hip_bfloat16* hq)
{
    float u0, u1, u2, u3;
    unsigned a0 = u.x << 16, a1 = u.x & 0xffff0000u;
    unsigned a2 = u.y << 16, a3 = u.y & 0xffff0000u;
    __builtin_memcpy(&u0, &a0, 4); __builtin_memcpy(&u1, &a1, 4);
    __builtin_memcpy(&u2, &a2, 4); __builtin_memcpy(&u3, &a3, 4);
    const float nf0 = __builtin_fmaf(-LOG2E_F, u1, nbf);
    const float nr0 = __builtin_fmaf(-LOG2E_F, u2, nbr);
    const float ef = __builtin_amdgcn_exp2f(__builtin_fmaf(nvf, c, nf0));
    const float er = __builtin_amdgcn_exp2f(__builtin_fmaf(nvr, c, nr0));
    const float f  = __builtin_amdgcn_rcpf(1.0f + ef);
    const float r  = __builtin_amdgcn_rcpf(1.0f + er);
    const float c2 = __builtin_fmaf(f, c - u0, u0);
    const float hv = __builtin_fmaf(r, c2 - u3, u3);
    *hq = __float2bfloat16(hv);
    return c2;
}

__global__ __launch_bounds__(256) void sru_scan(
    const __hip_bfloat16* __restrict__ U2,
    const float* __restrict__ wc,    // (2,2,H)
    const float* __restrict__ bias,  // (2,2,H)
    __hip_bfloat16* __restrict__ hout)
{
    __shared__ __align__(16) char lds[2 * SCAN_S * 512];   // 65536 B
    const int tid  = threadIdx.x;
    const int wave = tid >> 6;
    const int lane = tid & 63;
    const int beta = blockIdx.x;
    const int b    = beta >> 3;
    const int dir  = (beta >> 2) & 1;
    const int hg   = beta & 3;
    const int h    = hg * 64 + lane;

    const char* gslice = (const char*)U2 + (size_t)beta * (1024 * 512);

    const float nvf = -LOG2E_F * wc[(dir * 2 + 0) * H_DIM + h];
    const float nvr = -LOG2E_F * wc[(dir * 2 + 1) * H_DIM + h];
    const float nbf = -LOG2E_F * bias[(dir * 2 + 0) * H_DIM + h];
    const float nbr = -LOG2E_F * bias[(dir * 2 + 1) * H_DIM + h];
    __hip_bfloat16* hp = hout + ((long)(b * 1024 + (dir ? 1023 : 0))) * 512 + dir * 256 + h;
    const long hstep = dir ? -512L : 512L;
    float c = 0.0f;

    const int plane = lane & 31;            // producer: byte slot within a step

    // prologue: producers async-fill half 0 with batch 0
    if (wave > 0) {
        for (int p = wave - 1; p < SCAN_S / 2; p += 3) {
            const int sl = 2 * p + (lane >> 5);
            const int t  = dir ? (1023 - sl) : sl;
            gload_lds16(gslice + (size_t)t * 512 + plane * 16, lds + p * 1024);
        }
    }
    __syncthreads();

    for (int bat = 0; bat < SCAN_NB; ++bat) {
        if (wave > 0) {
            if (bat + 1 < SCAN_NB) {
                char* halfN = lds + ((bat + 1) & 1) * (SCAN_S * 512);
                const int tb = (bat + 1) * SCAN_S;
                for (int p = wave - 1; p < SCAN_S / 2; p += 3) {
                    const int sl = tb + 2 * p + (lane >> 5);
                    const int t  = dir ? (1023 - sl) : sl;
                    gload_lds16(gslice + (size_t)t * 512 + plane * 16,
                                halfN + p * 1024);
                }
            }
        } else {
            const char* half = lds + (bat & 1) * (SCAN_S * 512);
            __hip_bfloat16* hq = hp + (long)(bat * SCAN_S) * hstep;
            uint2 qa[GRP], qb[GRP];
            // grouped loads: 16 independent ds_read_b64 ahead of each chain run
#pragma unroll
            for (int j = 0; j < GRP; ++j)
                qa[j] = *(const uint2*)(half + (0 * GRP + j) * 512 + (lane << 3));
#pragma unroll
            for (int j = 0; j < GRP; ++j)
                qb[j] = *(const uint2*)(half + (1 * GRP + j) * 512 + (lane << 3));
#pragma unroll
            for (int j = 0; j < GRP; ++j)
                c = scan_step(qa[j], c, nvf, nvr, nbf, nbr, hq + (long)j * hstep);
#pragma unroll
            for (int j = 0; j < GRP; ++j)
                qa[j] = *(const uint2*)(half + (2 * GRP + j) * 512 + (lane << 3));
#pragma unroll
            for (int j = 0; j < GRP; ++j)
                c = scan_step(qb[j], c, nvf, nvr, nbf, nbr, hq + (long)(GRP + j) * hstep);
#pragma unroll
            for (int j = 0; j < GRP; ++j)
                qb[j] = *(const uint2*)(half + (3 * GRP + j) * 512 + (lane << 3));
#pragma unroll
            for (int j = 0; j < GRP; ++j)
                c = scan_step(qa[j], c, nvf, nvr, nbf, nbr, hq + (long)(2 * GRP + j) * hstep);
#pragma unroll
            for (int j = 0; j < GRP; ++j)
                c = scan_step(qb[j], c, nvf, nvr, nbf, nbr, hq + (long)(3 * GRP + j) * hstep);
        }
        __syncthreads();   // producers' vmcnt drain + ring-half protection
    }
}

// ---------------------------------------------------------------------------
// MFMA logits + log_softmax. Block = 256 threads, 128 rows. K=256, N=32.
__global__ __launch_bounds__(256) void logits_mfma(
    const __hip_bfloat16* __restrict__ fc,    // (M_ROWS,256) bf16
    const __hip_bfloat16* __restrict__ lpwb,  // (32,256) bf16, padded
    const float* __restrict__ lpb,            // (21,)
    float* __restrict__ out)
{
    __shared__ __align__(16) char smb[25088];
    const int tid  = threadIdx.x;
    const int lane = tid & 63;
    const int wave = tid >> 6;
    const long m0  = (long)blockIdx.x * 128;

    for (int idx = tid; idx < 32 * 32; idx += 256) {
        const int rw = idx >> 5, sl = idx & 31;
        *(bf16x8*)(smb + rw * 528 + sl * 16) =
            *(const bf16x8*)(lpwb + rw * 256 + sl * 8);
    }

    const int ldrow = lane >> 2;
    const int ldq   = lane & 3;
    const int gq    = ldq ^ ((ldrow >> 1) & 3);
    const int gkoff = gq * 8;

    const int fr = lane & 15;
    const int kq = lane >> 4;
    const int sw = (kq ^ ((fr >> 1) & 3)) * 16;

    f32x4 acc[2][2] = {};
    for (int kc = 0; kc < 8; ++kc) {
        __syncthreads();
#pragma unroll
        for (int i = 0; i < 2; ++i) {
            const int rc = wave * 2 + i;
            gload_lds16(fc + (m0 + rc * 16 + ldrow) * 256 + kc * 32 + gkoff,
                        smb + 16896 + rc * 1024);
        }
        __syncthreads();
        bf16x8 af[2], bfv[2];
#pragma unroll
        for (int i = 0; i < 2; ++i)
            af[i] = *(const bf16x8*)(smb + 16896 + (wave * 2 + i) * 1024 + fr * 64 + sw);
#pragma unroll
        for (int j = 0; j < 2; ++j)
            bfv[j] = *(const bf16x8*)(smb + (j * 16 + fr) * 528 + kc * 64 + kq * 16);
#pragma unroll
        for (int i = 0; i < 2; ++i)
#pragma unroll
            for (int j = 0; j < 2; ++j)
                acc[i][j] = __builtin_amdgcn_mfma_f32_16x16x32_bf16(
                    af[i], bfv[j], acc[i][j], 0, 0, 0);
    }

    __syncthreads();
    float* smC = (float*)smb;                  // stride 36 f32
    const int col_l = lane & 15;
    const int row_l = (lane >> 4) * 4;
#pragma unroll
    for (int j = 0; j < 2; ++j) {
        const int gc = j * 16 + col_l;
        const float bv = (gc < AA_DIM) ? lpb[gc] : 0.0f;
#pragma unroll
        for (int i = 0; i < 2; ++i)
#pragma unroll
            for (int r = 0; r < 4; ++r)
                smC[(wave * 32 + i * 16 + row_l + r) * 36 + gc] = acc[i][j][r] + bv;
    }
    __syncthreads();
    if (tid < 128) {
        const float* rowp = smC + tid * 36;
        float m = rowp[0];
#pragma unroll
        for (int a = 1; a < AA_DIM; ++a) m = fmaxf(m, rowp[a]);
        float s = 0.0f;
#pragma unroll
        for (int a = 0; a < AA_DIM; ++a) s += __expf(rowp[a] - m);
        const float lse = __logf(s) + m;
        float* op = out + (m0 + tid) * AA_DIM;
#pragma unroll
        for (int a = 0; a < AA_DIM; ++a) op[a] = rowp[a] - lse;
    }
}

// ---------------------------------------------------------------------------
extern "C" void kernel_launch(void* const* d_in, const int* in_sizes, int n_in,
                              void* d_out, int out_size, void* d_ws, size_t ws_size,
                              hipStream_t stream)
{
    const float* x     = (const float*)d_in[0];
    const float* w_l0  = (const float*)d_in[2];
    const float* wc_l0 = (const float*)d_in[3];
    const float* b_l0  = (const float*)d_in[4];
    const float* w_l1  = (const float*)d_in[5];
    const float* wc_l1 = (const float*)d_in[6];
    const float* b_l1  = (const float*)d_in[7];
    const float* fc1_w = (const float*)d_in[8];
    const float* fc1_b = (const float*)d_in[9];
    const float* lp_w  = (const float*)d_in[10];
    const float* lp_b  = (const float*)d_in[11];
    float* out = (float*)d_out;

    char* ws = (char*)d_ws;
    __hip_bfloat16* U      = (__hip_bfloat16*)(ws);              // 134,217,728 B (U2 layout)
    __hip_bfloat16* h0b    = (__hip_bfloat16*)(ws + 134217728);  //  33,554,432
    __hip_bfloat16* h1b    = (__hip_bfloat16*)(ws + 167772160);  //  33,554,432
    __hip_bfloat16* xb     = (__hip_bfloat16*)(ws + 201326592);  //  16,777,216
    __hip_bfloat16* fcob   = xb;                                 //  alias after GEMM0
    __hip_bfloat16* w0t    = (__hip_bfloat16*)(ws + 218103808);  //  (2048,256)
    __hip_bfloat16* w1t    = (__hip_bfloat16*)(ws + 219152384);  //  (2048,512)
    __hip_bfloat16* fc1wb  = (__hip_bfloat16*)(ws + 221249536);  //  (256,512)
    __hip_bfloat16* lpwb   = (__hip_bfloat16*)(ws + 221511680);  //  (32,256)

    cvt_all<<<(CVT_TOT + 255) / 256, 256, 0, stream>>>(
        x, w_l0, w_l1, fc1_w, lp_w, xb, w0t, w1t, fc1wb, lpwb);

    // U-GEMMs write U2 layout; grid = MB*NB (1-D), MB=256, NB=16, nbShift=4
    gemm_bf16<1><<<4096, 256, 0, stream>>>(
        xb, w0t, nullptr, U, M_ROWS, 2048, DIN_DIM, 4);
    sru_scan<<<256, 256, 0, stream>>>(U, wc_l0, b_l0, h0b);
    gemm_bf16<1><<<4096, 256, 0, stream>>>(
        h0b, w1t, nullptr, U, M_ROWS, 2048, 512, 4);
    sru_scan<<<256, 256, 0, stream>>>(U, wc_l1, b_l1, h1b);
    // fc GEMM: plain layout, NB=2 -> 512 blocks, nbShift=1
    gemm_bf16<0><<<512, 256, 0, stream>>>(
        h1b, fc1wb, fc1_b, fcob, M_ROWS, 256, 512, 1);
    logits_mfma<<<M_ROWS / 128, 256, 0, stream>>>(fcob, lpwb, lp_b, out);
}